// Round 3
// baseline (883.108 us; speedup 1.0000x reference)
//
#include <hip/hip_runtime.h>
#include <hip/hip_bf16.h>

#define HH 96
#define WW 96
#define NPX 9216          // HH*WW
#define NC 21             // classes
#define CP 24             // channels padded to 24 floats (96B) per i in LDS
#define RAD 35
#define TAPS 71

// bilateral tiling: 192 threads * 4 j per lane = 768 j per block; 12 j-blocks
#define BT 192
#define JB 4
#define JBLK 12
#define BCHUNK 64
#define BNI 144           // 9216/64

// rowsum tiling
#define RCHUNK 32
#define RNI 288

// normalized separable 1D gaussian taps g[|d|], d=0..35 (exp(-d^2/72)/S, S=15.03977)
__device__ const float GN[36] = {
    6.64904e-02f, 6.55733e-02f, 6.28973e-02f, 5.86776e-02f, 5.32413e-02f,
    4.69853e-02f, 4.03286e-02f, 3.36665e-02f, 2.73351e-02f, 2.15863e-02f,
    1.65795e-02f, 1.23852e-02f, 8.99851e-03f, 6.35877e-03f, 4.37031e-03f,
    2.92139e-03f, 1.89933e-03f, 1.20102e-03f, 7.38645e-04f, 4.41830e-04f,
    2.57057e-04f, 1.45461e-04f, 8.00452e-05f, 4.28451e-05f, 2.23052e-05f,
    1.12939e-05f, 5.56182e-06f, 2.66396e-06f, 1.24101e-06f, 5.62291e-07f,
    2.47787e-07f, 1.06203e-07f, 4.42716e-08f, 1.79497e-08f, 7.07818e-09f,
    2.71479e-09f
};

__device__ __forceinline__ bool is_bf16(const void* kstd_raw){
    return (((const unsigned int*)kstd_raw)[0] & 0xFFFFu) != 0u;
}
__device__ __forceinline__ float ld_in(const void* p, int i, bool bf){
    if (bf){
        unsigned int u = ((unsigned int)((const unsigned short*)p)[i]) << 16;
        return __uint_as_float(u);
    }
    return ((const float*)p)[i];
}

// ---------- features (scaled so w = exp2(-sum diff^2) = exp(-0.5 d2)); also zeroes nacc ----------
__global__ __launch_bounds__(256) void feat_kernel(const void* __restrict__ ref_raw,
                                                   const void* __restrict__ kstd_raw,
                                                   float* __restrict__ feat,
                                                   float* __restrict__ nacc){
    int i = blockIdx.x*256 + threadIdx.x;
    if (i >= NPX) return;
    bool bf = is_bf16(kstd_raw);
    const float SCL = 0.84932180028801907f; // sqrt(0.5*log2(e))
    int y = i / WW, x = i - y*WW;
    float inv0 = SCL / ld_in(kstd_raw, 0, bf);
    float inv1 = SCL / ld_in(kstd_raw, 1, bf);
    float inv2 = SCL / ld_in(kstd_raw, 2, bf);
    float inv3 = SCL / ld_in(kstd_raw, 3, bf);
    float inv4 = SCL / ld_in(kstd_raw, 4, bf);
    feat[i*8+0] = (float)y * inv0;
    feat[i*8+1] = (float)x * inv1;
    feat[i*8+2] = ld_in(ref_raw, 0*NPX+i, bf) * inv2;
    feat[i*8+3] = ld_in(ref_raw, 1*NPX+i, bf) * inv3;
    feat[i*8+4] = ld_in(ref_raw, 2*NPX+i, bf) * inv4;
    feat[i*8+5] = 0.f; feat[i*8+6] = 0.f; feat[i*8+7] = 0.f;
    nacc[i] = 0.f;
}

// ---------- U = log(clip(u)), q0 = softmax(U); also zeroes qbf ----------
__global__ __launch_bounds__(256) void init_kernel(const void* __restrict__ unary_raw,
                                                   const void* __restrict__ kstd_raw,
                                                   float* __restrict__ U, float* __restrict__ q,
                                                   float* __restrict__ qbf){
    int j = blockIdx.x*256 + threadIdx.x;
    if (j >= NPX) return;
    bool bf = is_bf16(kstd_raw);
    float u[NC]; float m = -1e30f;
    #pragma unroll
    for (int c = 0; c < NC; ++c){
        float v = ld_in(unary_raw, c*NPX+j, bf);
        v = fminf(fmaxf(v, 1e-5f), 1.0f);
        float lg = logf(v);
        U[c*NPX+j] = lg;
        u[c] = lg;
        m = fmaxf(m, lg);
        qbf[c*NPX+j] = 0.f;
    }
    float s = 0.f;
    #pragma unroll
    for (int c = 0; c < NC; ++c){ u[c] = expf(u[c]-m); s += u[c]; }
    float inv = 1.f/s;
    #pragma unroll
    for (int c = 0; c < NC; ++c) q[c*NPX+j] = u[c]*inv;
}

// ---------- rowsum of K (for norm) ----------
__global__ __launch_bounds__(256) void rowsum_kernel(const float* __restrict__ feat,
                                                     float* __restrict__ nacc){
    __shared__ __align__(16) float s_feat[RNI*8];
    int tid = threadIdx.x;
    int i0 = blockIdx.y * RNI;
    for (int s = tid; s < RNI*8; s += 256) s_feat[s] = feat[i0*8 + s];
    __syncthreads();
    int j = blockIdx.x*256 + tid;
    float4 fj = *(const float4*)(feat + j*8);
    float fj4 = feat[j*8+4];
    float a = 0.f;
    #pragma unroll 2
    for (int ii = 0; ii < RNI; ++ii){
        const float* sf = s_feat + ii*8;
        float dx = fj.x - sf[0], dy = fj.y - sf[1], dz = fj.z - sf[2], dw = fj.w - sf[3], d4 = fj4 - sf[4];
        float d2 = dx*dx + dy*dy + dz*dz + dw*dw + d4*d4;
        a += exp2f(-d2);
    }
    atomicAdd(&nacc[j], a);
}

__global__ __launch_bounds__(256) void normfin_kernel(const float* __restrict__ nacc,
                                                      float* __restrict__ rnorm){
    int j = blockIdx.x*256 + threadIdx.x;
    if (j >= NPX) return;
    rnorm[j] = 1.0f / (sqrtf(nacc[j]) + 1e-8f);
}

// ---------- horizontal / vertical 1D gaussian conv (zero padded), taps baked ----------
__global__ __launch_bounds__(256) void convh_kernel(const float* __restrict__ q,
                                                    float* __restrict__ o){
    int idx = blockIdx.x*256 + threadIdx.x;
    if (idx >= NC*NPX) return;
    int c = idx / NPX; int p = idx - c*NPX; int y = p / WW; int x = p - y*WW;
    const float* row = q + c*NPX + y*WW;
    int tlo = max(0, RAD - x);
    int thi = min(TAPS-1, RAD + (WW-1) - x);
    float a = 0.f;
    for (int t = tlo; t <= thi; ++t) a += GN[abs(t-RAD)]*row[x + t - RAD];
    o[idx] = a;
}

__global__ __launch_bounds__(256) void convv_kernel(const float* __restrict__ q,
                                                    float* __restrict__ o){
    int idx = blockIdx.x*256 + threadIdx.x;
    if (idx >= NC*NPX) return;
    int c = idx / NPX; int p = idx - c*NPX; int y = p / WW; int x = p - y*WW;
    const float* col = q + c*NPX + x;
    int tlo = max(0, RAD - y);
    int thi = min(TAPS-1, RAD + (HH-1) - y);
    float a = 0.f;
    for (int t = tlo; t <= thi; ++t) a += GN[abs(t-RAD)]*col[(y + t - RAD)*WW];
    o[idx] = a;
}

// ---------- dense bilateral, 4 j per lane: qbf[c,j] += sum_i exp2(-||fi-fj||^2) * q[c,i]*rnorm[i] ----------
__global__ __launch_bounds__(BT, 3) void bilateral_kernel(const float* __restrict__ q,
                                                          const float* __restrict__ feat,
                                                          const float* __restrict__ rnorm,
                                                          float* __restrict__ qbf){
    __shared__ __align__(16) float s_feat[BNI*8];
    __shared__ __align__(16) float s_tmp[BNI*CP];
    int tid = threadIdx.x;
    int i0 = blockIdx.y * BNI;
    for (int s = tid; s < BNI*8; s += BT) s_feat[s] = feat[i0*8 + s];
    for (int ii = tid; ii < BNI; ii += BT){
        float rn = rnorm[i0+ii];
        #pragma unroll
        for (int c = 0; c < NC; ++c) s_tmp[ii*CP+c] = q[c*NPX + i0+ii] * rn;
    }
    __syncthreads();

    int jbase = blockIdx.x*(BT*JB) + tid;
    float fj[JB][5];
    #pragma unroll
    for (int jb = 0; jb < JB; ++jb){
        const float* fp = feat + (jbase + jb*BT)*8;
        float4 v = *(const float4*)fp;
        fj[jb][0]=v.x; fj[jb][1]=v.y; fj[jb][2]=v.z; fj[jb][3]=v.w; fj[jb][4]=fp[4];
    }
    float acc[JB][NC];
    #pragma unroll
    for (int jb = 0; jb < JB; ++jb)
        #pragma unroll
        for (int c = 0; c < NC; ++c) acc[jb][c] = 0.f;

    for (int ii = 0; ii < BNI; ++ii){
        const float* sf = s_feat + ii*8;
        float4 f0 = *(const float4*)sf;
        float f4 = sf[4];
        float w[JB];
        #pragma unroll
        for (int jb = 0; jb < JB; ++jb){
            float dx = fj[jb][0]-f0.x, dy = fj[jb][1]-f0.y, dz = fj[jb][2]-f0.z,
                  dw = fj[jb][3]-f0.w, d4 = fj[jb][4]-f4;
            w[jb] = exp2f(-(dx*dx + dy*dy + dz*dz + dw*dw + d4*d4));
        }
        const float4* tp = (const float4*)(s_tmp + ii*CP);
        float4 t0 = tp[0], t1 = tp[1], t2 = tp[2], t3 = tp[3], t4 = tp[4];
        float t20 = s_tmp[ii*CP+20];
        float t[NC] = { t0.x,t0.y,t0.z,t0.w, t1.x,t1.y,t1.z,t1.w,
                        t2.x,t2.y,t2.z,t2.w, t3.x,t3.y,t3.z,t3.w,
                        t4.x,t4.y,t4.z,t4.w, t20 };
        #pragma unroll
        for (int jb = 0; jb < JB; ++jb){
            float wj = w[jb];
            #pragma unroll
            for (int c = 0; c < NC; ++c) acc[jb][c] += wj * t[c];
        }
    }
    #pragma unroll
    for (int jb = 0; jb < JB; ++jb){
        int j = jbase + jb*BT;
        #pragma unroll
        for (int c = 0; c < NC; ++c) atomicAdd(&qbf[c*NPX + j], acc[jb][c]);
    }
}

// ---------- q_hat = U + 4*qbf*rnorm_j + 2*qsf ; softmax; zero qbf for next iter ----------
__global__ __launch_bounds__(256) void combine_kernel(const float* __restrict__ U,
                                                      float* __restrict__ qbf,
                                                      const float* __restrict__ qsf,
                                                      const float* __restrict__ rnorm,
                                                      float* __restrict__ qn,
                                                      void* __restrict__ outp,
                                                      const void* __restrict__ kstd_raw){
    int j = blockIdx.x*256 + threadIdx.x;
    if (j >= NPX) return;
    float rn = rnorm[j];
    float h[NC]; float m = -1e30f;
    #pragma unroll
    for (int c = 0; c < NC; ++c){
        float v = U[c*NPX+j] + 4.0f*qbf[c*NPX+j]*rn + 2.0f*qsf[c*NPX+j];
        qbf[c*NPX+j] = 0.f;             // ready for next iteration's bilateral
        h[c] = v; m = fmaxf(m, v);
    }
    float s = 0.f;
    #pragma unroll
    for (int c = 0; c < NC; ++c){ h[c] = expf(h[c]-m); s += h[c]; }
    float inv = 1.f/s;
    bool bf = outp ? is_bf16(kstd_raw) : false;
    #pragma unroll
    for (int c = 0; c < NC; ++c){
        float v = h[c]*inv;
        qn[c*NPX+j] = v;
        if (outp){
            if (bf) ((__hip_bfloat16*)outp)[c*NPX+j] = __float2bfloat16(v);
            else    ((float*)outp)[c*NPX+j] = v;
        }
    }
}

extern "C" void kernel_launch(void* const* d_in, const int* in_sizes, int n_in,
                              void* d_out, int out_size, void* d_ws, size_t ws_size,
                              hipStream_t stream) {
    const void* unary_raw = d_in[0];
    const void* ref_raw   = d_in[1];
    const void* kstd_raw  = d_in[2];

    float* w = (float*)d_ws;
    float* feat  = w; w += NPX*8;
    float* U     = w; w += NC*NPX;
    float* qA    = w; w += NC*NPX;
    float* qB    = w; w += NC*NPX;
    float* t1b   = w; w += NC*NPX;
    float* qsf   = w; w += NC*NPX;
    float* qbf   = w; w += NC*NPX;
    float* nacc  = w; w += NPX;
    float* rnorm = w; w += NPX;

    hipLaunchKernelGGL(feat_kernel, dim3(36), dim3(256), 0, stream, ref_raw, kstd_raw, feat, nacc);
    hipLaunchKernelGGL(init_kernel, dim3(36), dim3(256), 0, stream, unary_raw, kstd_raw, U, qA, qbf);
    hipLaunchKernelGGL(rowsum_kernel, dim3(36, RCHUNK), dim3(256), 0, stream, feat, nacc);
    hipLaunchKernelGGL(normfin_kernel, dim3(36), dim3(256), 0, stream, nacc, rnorm);

    float* qc = qA; float* qn = qB;
    for (int it = 0; it < 5; ++it){
        hipLaunchKernelGGL(convh_kernel, dim3(756), dim3(256), 0, stream, qc, t1b);
        hipLaunchKernelGGL(convv_kernel, dim3(756), dim3(256), 0, stream, t1b, qsf);
        hipLaunchKernelGGL(bilateral_kernel, dim3(JBLK, BCHUNK), dim3(BT), 0, stream, qc, feat, rnorm, qbf);
        hipLaunchKernelGGL(combine_kernel, dim3(36), dim3(256), 0, stream,
                           U, qbf, qsf, rnorm, qn, (it == 4) ? d_out : (void*)nullptr, kstd_raw);
        float* tswap = qc; qc = qn; qn = tswap;
    }
}

// Round 4
// 627.609 us; speedup vs baseline: 1.4071x; 1.4071x over previous
//
#include <hip/hip_runtime.h>
#include <hip/hip_bf16.h>

#define HH 96
#define WW 96
#define NPX 9216          // HH*WW
#define NC 21             // classes
#define CP 24             // channels padded to 24 floats per i in LDS

// bilateral tiling: 256 threads, 1 j per lane; i split into 64 chunks of 144
#define BT 256
#define BCHUNK 64
#define BNI 144           // 9216/64

// truncated separable gaussian: radius 24 (tail mass ~1.8e-4, well under tolerance)
#define RAD2 24
#define TAPS2 49

// normalized separable 1D gaussian taps g[|d|], d=0..35 (exp(-d^2/72)/S, S=15.03977)
__device__ const float GN[36] = {
    6.64904e-02f, 6.55733e-02f, 6.28973e-02f, 5.86776e-02f, 5.32413e-02f,
    4.69853e-02f, 4.03286e-02f, 3.36665e-02f, 2.73351e-02f, 2.15863e-02f,
    1.65795e-02f, 1.23852e-02f, 8.99851e-03f, 6.35877e-03f, 4.37031e-03f,
    2.92139e-03f, 1.89933e-03f, 1.20102e-03f, 7.38645e-04f, 4.41830e-04f,
    2.57057e-04f, 1.45461e-04f, 8.00452e-05f, 4.28451e-05f, 2.23052e-05f,
    1.12939e-05f, 5.56182e-06f, 2.66396e-06f, 1.24101e-06f, 5.62291e-07f,
    2.47787e-07f, 1.06203e-07f, 4.42716e-08f, 1.79497e-08f, 7.07818e-09f,
    2.71479e-09f
};

__device__ __forceinline__ bool is_bf16(const void* kstd_raw){
    return (((const unsigned int*)kstd_raw)[0] & 0xFFFFu) != 0u;
}
__device__ __forceinline__ float ld_in(const void* p, int i, bool bf){
    if (bf){
        unsigned int u = ((unsigned int)((const unsigned short*)p)[i]) << 16;
        return __uint_as_float(u);
    }
    return ((const float*)p)[i];
}

// ---------- setup: features (+ sq in slot5), U=log(clip(u)), q0=softmax(U), zero qbf/nacc ----------
__global__ __launch_bounds__(256) void setup_kernel(const void* __restrict__ unary_raw,
                                                    const void* __restrict__ ref_raw,
                                                    const void* __restrict__ kstd_raw,
                                                    float* __restrict__ feat,
                                                    float* __restrict__ U, float* __restrict__ q,
                                                    float* __restrict__ qbf,
                                                    float* __restrict__ nacc){
    int i = blockIdx.x*256 + threadIdx.x;
    if (i >= NPX) return;
    bool bf = is_bf16(kstd_raw);
    const float SCL = 0.84932180028801907f; // sqrt(0.5*log2(e))
    int y = i / WW, x = i - y*WW;
    float f0 = (float)y * (SCL / ld_in(kstd_raw, 0, bf));
    float f1 = (float)x * (SCL / ld_in(kstd_raw, 1, bf));
    float f2 = ld_in(ref_raw, 0*NPX+i, bf) * (SCL / ld_in(kstd_raw, 2, bf));
    float f3 = ld_in(ref_raw, 1*NPX+i, bf) * (SCL / ld_in(kstd_raw, 3, bf));
    float f4 = ld_in(ref_raw, 2*NPX+i, bf) * (SCL / ld_in(kstd_raw, 4, bf));
    feat[i*8+0] = f0; feat[i*8+1] = f1; feat[i*8+2] = f2; feat[i*8+3] = f3; feat[i*8+4] = f4;
    feat[i*8+5] = f0*f0 + f1*f1 + f2*f2 + f3*f3 + f4*f4;   // |f|^2
    feat[i*8+6] = 0.f; feat[i*8+7] = 0.f;
    nacc[i] = 0.f;

    float u[NC]; float m = -1e30f;
    #pragma unroll
    for (int c = 0; c < NC; ++c){
        float v = ld_in(unary_raw, c*NPX+i, bf);
        v = fminf(fmaxf(v, 1e-5f), 1.0f);
        float lg = logf(v);
        U[c*NPX+i] = lg;
        u[c] = lg;
        m = fmaxf(m, lg);
        qbf[c*NPX+i] = 0.f;
    }
    float s = 0.f;
    #pragma unroll
    for (int c = 0; c < NC; ++c){ u[c] = expf(u[c]-m); s += u[c]; }
    float inv = 1.f/s;
    #pragma unroll
    for (int c = 0; c < NC; ++c) q[c*NPX+i] = u[c]*inv;
}

// ---------- rowsum of K (for norm), dot-form ----------
__global__ __launch_bounds__(256) void rowsum_kernel(const float* __restrict__ feat,
                                                     float* __restrict__ nacc){
    __shared__ __align__(16) float s_feat[BNI*8];
    int tid = threadIdx.x;
    int i0 = blockIdx.y * BNI;
    for (int s = tid; s < BNI*2; s += 256)
        ((float4*)s_feat)[s] = ((const float4*)(feat + i0*8))[s];
    __syncthreads();
    int j = blockIdx.x*256 + tid;
    float4 fj = *(const float4*)(feat + j*8);
    float2 fj45 = *(const float2*)(feat + j*8 + 4);
    float fj4 = fj45.x, sqj = fj45.y;
    float a = 0.f;
    #pragma unroll 4
    for (int ii = 0; ii < BNI; ++ii){
        const float* sf = s_feat + ii*8;
        float4 f0 = *(const float4*)sf;
        float2 f45 = *(const float2*)(sf+4);
        float dot = fj.x*f0.x + fj.y*f0.y + fj.z*f0.z + fj.w*f0.w + fj4*f45.x;
        float d2 = fmaxf(sqj + f45.y - 2.0f*dot, 0.f);
        a += exp2f(-d2);
    }
    atomicAdd(&nacc[j], a);
}

__global__ __launch_bounds__(256) void normfin_kernel(const float* __restrict__ nacc,
                                                      float* __restrict__ rnorm){
    int j = blockIdx.x*256 + threadIdx.x;
    if (j >= NPX) return;
    rnorm[j] = 1.0f / (sqrtf(nacc[j]) + 1e-8f);
}

// ---------- horizontal / vertical 1D gaussian conv (zero padded, radius 24) ----------
__global__ __launch_bounds__(256) void convh_kernel(const float* __restrict__ q,
                                                    float* __restrict__ o){
    int idx = blockIdx.x*256 + threadIdx.x;
    if (idx >= NC*NPX) return;
    int c = idx / NPX; int p = idx - c*NPX; int y = p / WW; int x = p - y*WW;
    const float* row = q + c*NPX + y*WW;
    int tlo = max(0, RAD2 - x);
    int thi = min(TAPS2-1, RAD2 + (WW-1) - x);
    float a = 0.f;
    for (int t = tlo; t <= thi; ++t) a += GN[abs(t-RAD2)]*row[x + t - RAD2];
    o[idx] = a;
}

__global__ __launch_bounds__(256) void convv_kernel(const float* __restrict__ q,
                                                    float* __restrict__ o){
    int idx = blockIdx.x*256 + threadIdx.x;
    if (idx >= NC*NPX) return;
    int c = idx / NPX; int p = idx - c*NPX; int y = p / WW; int x = p - y*WW;
    const float* col = q + c*NPX + x;
    int tlo = max(0, RAD2 - y);
    int thi = min(TAPS2-1, RAD2 + (HH-1) - y);
    float a = 0.f;
    for (int t = tlo; t <= thi; ++t) a += GN[abs(t-RAD2)]*col[(y + t - RAD2)*WW];
    o[idx] = a;
}

// ---------- dense bilateral: qbf[c,j] += sum_i exp2(-(sqi+sqj-2 fi.fj)) * q[c,i]*rnorm[i] ----------
__global__ __launch_bounds__(256) void bilateral_kernel(const float* __restrict__ q,
                                                        const float* __restrict__ feat,
                                                        const float* __restrict__ rnorm,
                                                        float* __restrict__ qbf){
    __shared__ __align__(16) float s_feat[BNI*8];
    __shared__ __align__(16) float s_tmp[BNI*CP];
    int tid = threadIdx.x;
    int i0 = blockIdx.y * BNI;
    for (int s = tid; s < BNI*2; s += BT)
        ((float4*)s_feat)[s] = ((const float4*)(feat + i0*8))[s];
    for (int ii = tid; ii < BNI; ii += BT){
        float rn = rnorm[i0+ii];
        #pragma unroll
        for (int c = 0; c < NC; ++c) s_tmp[ii*CP+c] = q[c*NPX + i0+ii] * rn;
    }
    __syncthreads();

    int j = blockIdx.x*BT + tid;
    float4 fj = *(const float4*)(feat + j*8);
    float2 fj45 = *(const float2*)(feat + j*8 + 4);
    float fj4 = fj45.x, sqj = fj45.y;
    float4 a0 = {0.f,0.f,0.f,0.f}, a1 = a0, a2 = a0, a3 = a0, a4 = a0;
    float a20 = 0.f;
    #pragma unroll 2
    for (int ii = 0; ii < BNI; ++ii){
        const float* sf = s_feat + ii*8;
        float4 f0 = *(const float4*)sf;
        float2 f45 = *(const float2*)(sf+4);
        float dot = fj.x*f0.x + fj.y*f0.y + fj.z*f0.z + fj.w*f0.w + fj4*f45.x;
        float d2 = fmaxf(sqj + f45.y - 2.0f*dot, 0.f);
        float wgt = exp2f(-d2);
        const float4* tp = (const float4*)(s_tmp + ii*CP);
        float4 t0 = tp[0], t1 = tp[1], t2 = tp[2], t3 = tp[3], t4 = tp[4];
        float t20 = s_tmp[ii*CP+20];
        a0.x += wgt*t0.x; a0.y += wgt*t0.y; a0.z += wgt*t0.z; a0.w += wgt*t0.w;
        a1.x += wgt*t1.x; a1.y += wgt*t1.y; a1.z += wgt*t1.z; a1.w += wgt*t1.w;
        a2.x += wgt*t2.x; a2.y += wgt*t2.y; a2.z += wgt*t2.z; a2.w += wgt*t2.w;
        a3.x += wgt*t3.x; a3.y += wgt*t3.y; a3.z += wgt*t3.z; a3.w += wgt*t3.w;
        a4.x += wgt*t4.x; a4.y += wgt*t4.y; a4.z += wgt*t4.z; a4.w += wgt*t4.w;
        a20  += wgt*t20;
    }
    atomicAdd(&qbf[ 0*NPX+j], a0.x); atomicAdd(&qbf[ 1*NPX+j], a0.y);
    atomicAdd(&qbf[ 2*NPX+j], a0.z); atomicAdd(&qbf[ 3*NPX+j], a0.w);
    atomicAdd(&qbf[ 4*NPX+j], a1.x); atomicAdd(&qbf[ 5*NPX+j], a1.y);
    atomicAdd(&qbf[ 6*NPX+j], a1.z); atomicAdd(&qbf[ 7*NPX+j], a1.w);
    atomicAdd(&qbf[ 8*NPX+j], a2.x); atomicAdd(&qbf[ 9*NPX+j], a2.y);
    atomicAdd(&qbf[10*NPX+j], a2.z); atomicAdd(&qbf[11*NPX+j], a2.w);
    atomicAdd(&qbf[12*NPX+j], a3.x); atomicAdd(&qbf[13*NPX+j], a3.y);
    atomicAdd(&qbf[14*NPX+j], a3.z); atomicAdd(&qbf[15*NPX+j], a3.w);
    atomicAdd(&qbf[16*NPX+j], a4.x); atomicAdd(&qbf[17*NPX+j], a4.y);
    atomicAdd(&qbf[18*NPX+j], a4.z); atomicAdd(&qbf[19*NPX+j], a4.w);
    atomicAdd(&qbf[20*NPX+j], a20);
}

// ---------- q_hat = U + 4*qbf*rnorm_j + 2*qsf ; softmax; zero qbf for next iter ----------
__global__ __launch_bounds__(256) void combine_kernel(const float* __restrict__ U,
                                                      float* __restrict__ qbf,
                                                      const float* __restrict__ qsf,
                                                      const float* __restrict__ rnorm,
                                                      float* __restrict__ qn,
                                                      void* __restrict__ outp,
                                                      const void* __restrict__ kstd_raw){
    int j = blockIdx.x*256 + threadIdx.x;
    if (j >= NPX) return;
    float rn = rnorm[j];
    float h[NC]; float m = -1e30f;
    #pragma unroll
    for (int c = 0; c < NC; ++c){
        float v = U[c*NPX+j] + 4.0f*qbf[c*NPX+j]*rn + 2.0f*qsf[c*NPX+j];
        qbf[c*NPX+j] = 0.f;             // ready for next iteration's bilateral
        h[c] = v; m = fmaxf(m, v);
    }
    float s = 0.f;
    #pragma unroll
    for (int c = 0; c < NC; ++c){ h[c] = expf(h[c]-m); s += h[c]; }
    float inv = 1.f/s;
    bool bf = outp ? is_bf16(kstd_raw) : false;
    #pragma unroll
    for (int c = 0; c < NC; ++c){
        float v = h[c]*inv;
        qn[c*NPX+j] = v;
        if (outp){
            if (bf) ((__hip_bfloat16*)outp)[c*NPX+j] = __float2bfloat16(v);
            else    ((float*)outp)[c*NPX+j] = v;
        }
    }
}

extern "C" void kernel_launch(void* const* d_in, const int* in_sizes, int n_in,
                              void* d_out, int out_size, void* d_ws, size_t ws_size,
                              hipStream_t stream) {
    const void* unary_raw = d_in[0];
    const void* ref_raw   = d_in[1];
    const void* kstd_raw  = d_in[2];

    float* w = (float*)d_ws;
    float* feat  = w; w += NPX*8;
    float* U     = w; w += NC*NPX;
    float* qA    = w; w += NC*NPX;
    float* qB    = w; w += NC*NPX;
    float* t1b   = w; w += NC*NPX;
    float* qsf   = w; w += NC*NPX;
    float* qbf   = w; w += NC*NPX;
    float* nacc  = w; w += NPX;
    float* rnorm = w; w += NPX;

    hipLaunchKernelGGL(setup_kernel, dim3(36), dim3(256), 0, stream,
                       unary_raw, ref_raw, kstd_raw, feat, U, qA, qbf, nacc);
    hipLaunchKernelGGL(rowsum_kernel, dim3(36, BCHUNK), dim3(256), 0, stream, feat, nacc);
    hipLaunchKernelGGL(normfin_kernel, dim3(36), dim3(256), 0, stream, nacc, rnorm);

    float* qc = qA; float* qn = qB;
    for (int it = 0; it < 5; ++it){
        hipLaunchKernelGGL(convh_kernel, dim3(756), dim3(256), 0, stream, qc, t1b);
        hipLaunchKernelGGL(convv_kernel, dim3(756), dim3(256), 0, stream, t1b, qsf);
        hipLaunchKernelGGL(bilateral_kernel, dim3(36, BCHUNK), dim3(BT), 0, stream, qc, feat, rnorm, qbf);
        hipLaunchKernelGGL(combine_kernel, dim3(36), dim3(256), 0, stream,
                           U, qbf, qsf, rnorm, qn, (it == 4) ? d_out : (void*)nullptr, kstd_raw);
        float* tswap = qc; qc = qn; qn = tswap;
    }
}